// Round 21
// baseline (64.463 us; speedup 1.0000x reference)
//
#include <hip/hip_runtime.h>
#include <hip/hip_bf16.h>
#include <stdint.h>

#define NBATCH 16
#define NT 2048
#define NC 64
#define QT 64
#define KT 128
#define SC_LOG2E 11.5415603f  // 8 * log2(e)

typedef __bf16 bf16x8 __attribute__((ext_vector_type(8)));
typedef _Float16 f16x8 __attribute__((ext_vector_type(8)));
typedef float f32x4 __attribute__((ext_vector_type(4)));
typedef float f32x16 __attribute__((ext_vector_type(16)));

#define Z16 {0.f,0.f,0.f,0.f,0.f,0.f,0.f,0.f,0.f,0.f,0.f,0.f,0.f,0.f,0.f,0.f}

extern "C" __device__ float __ocml_native_exp2_f32(float);
#define EXP2F(x) __ocml_native_exp2_f32(x)

static __device__ __forceinline__ unsigned short f2bf(float f) {
  __bf16 h = (__bf16)f;
  union { __bf16 h; unsigned short u; } a; a.h = h; return a.u;
}
static __device__ __forceinline__ float bf2f(unsigned short h) {
  union { uint32_t u; float f; } a; a.u = ((uint32_t)h) << 16;
  return a.f;
}
static __device__ __forceinline__ unsigned short f2h(float f) {
  _Float16 h = (_Float16)f;  // v_cvt_f16_f32, RTNE
  union { _Float16 h; unsigned short u; } a; a.h = h; return a.u;
}
static __device__ __forceinline__ float h2f(unsigned short u) {
  union { unsigned short u; _Float16 h; } a; a.u = u; return (float)a.h;
}
static __device__ __forceinline__ float fasu(uint32_t u) {
  union { uint32_t u; float f; } a; a.u = u; return a.f;
}
static __device__ __forceinline__ uint32_t uasf(float f) {
  union { float f; uint32_t u; } a; a.f = f; return a.u;
}
static __device__ __forceinline__ uint32_t pkh(float a, float b) {
  auto h = __builtin_amdgcn_cvt_pkrtz(a, b);   // packed 2 x f16
  union { decltype(h) v; uint32_t u; } c; c.v = h; return c.u;
}

#define GLD_LDS16(gsrc, ldst)                                                  \
  __builtin_amdgcn_global_load_lds(                                            \
      (const __attribute__((address_space(1))) void*)(gsrc),                   \
      (__attribute__((address_space(3))) void*)(ldst), 16, 0, 0)

// ---------------------------------------------------------------------------
// Kernel 0: one-time W transpose + hi/lo bf16 split. 3 blocks (k,q,v).
// ---------------------------------------------------------------------------
__global__ __launch_bounds__(256, 2) void prep_w(
    const float* __restrict__ Wk, const float* __restrict__ Wq,
    const float* __restrict__ Wv,
    unsigned short* __restrict__ wt_hi, unsigned short* __restrict__ wt_lo)
{
  __shared__ unsigned short hbuf[64][66];
  __shared__ unsigned short lbuf[64][66];
  const int m = (int)blockIdx.x;
  const float* Wm = (m == 0) ? Wk : (m == 1 ? Wq : Wv);
  const int tid = (int)threadIdx.x;
  for (int idx = tid; idx < 1024; idx += 256) {
    int c = idx >> 4, o4 = (idx & 15) * 4;
    float4 v = *(const float4*)(Wm + c * 64 + o4);
    float vals[4] = {v.x, v.y, v.z, v.w};
#pragma unroll
    for (int j = 0; j < 4; ++j) {
      unsigned short h = f2bf(vals[j]);
      hbuf[o4 + j][c] = h;
      lbuf[o4 + j][c] = f2bf(vals[j] - bf2f(h));
    }
  }
  __syncthreads();
  for (int idx = tid; idx < 1024; idx += 256) {
    int o = idx >> 4, c0 = (idx & 15) * 4;
    ushort4 hv, lv;
    hv.x = hbuf[o][c0]; hv.y = hbuf[o][c0 + 1];
    hv.z = hbuf[o][c0 + 2]; hv.w = hbuf[o][c0 + 3];
    lv.x = lbuf[o][c0]; lv.y = lbuf[o][c0 + 1];
    lv.z = lbuf[o][c0 + 2]; lv.w = lbuf[o][c0 + 3];
    *(ushort4*)(wt_hi + (size_t)(m * 64 + o) * 64 + c0) = hv;
    *(ushort4*)(wt_lo + (size_t)(m * 64 + o) * 64 + c0) = lv;
  }
}

// ---------------------------------------------------------------------------
// Kernel 1: q,k,v projections. Internal math bf16 hi/lo MFMA (validated);
// outputs: kf (f16), qfh/qfl (f16 hi/lo of pre-scaled q), vt (f16, [B][64][T]).
// ---------------------------------------------------------------------------
__global__ __launch_bounds__(256, 2) void proj_kernel(
    const float* __restrict__ x,
    const unsigned short* __restrict__ wt_hi, const unsigned short* __restrict__ wt_lo,
    const float* __restrict__ bk, const float* __restrict__ bq, const float* __restrict__ bv,
    unsigned short* __restrict__ kf, unsigned short* __restrict__ qfh,
    unsigned short* __restrict__ qfl, unsigned short* __restrict__ vt)
{
  __shared__ __align__(16) char smem[65536];
  const int XH = 0, XL = 8192, WTH = 16384, WTL = 40960, VTB = 0; // VTB aliases XH
  const int tid = (int)threadIdx.x;
  const int l = tid & 63, w = tid >> 6;
  const int lr = l & 15, lg = l >> 4;
  const int blk = (int)blockIdx.x;
  const int rowbase = blk * 64;
  const int bb = blk >> 5;          // 32 blocks per batch

  float4 xv[4];
#pragma unroll
  for (int j = 0; j < 4; ++j) {
    int c = tid + j * 256;
    int row = c >> 4, d0 = (c & 15) * 4;
    xv[j] = *(const float4*)(x + (size_t)(rowbase + row) * NC + d0);
  }
#pragma unroll
  for (int ch4 = 0; ch4 < 6; ++ch4) {
    int ch = ch4 * 4 + w;
    int d = ch * 1024 + l * 16;
    int swk = d ^ (((d >> 7) & 7) << 4);
    GLD_LDS16((const char*)wt_hi + swk, smem + WTH + ch * 1024);
    GLD_LDS16((const char*)wt_lo + swk, smem + WTL + ch * 1024);
  }
#pragma unroll
  for (int j = 0; j < 4; ++j) {
    int c = tid + j * 256;
    int row = c >> 4, d0 = (c & 15) * 4;
    unsigned short h0 = f2bf(xv[j].x), h1 = f2bf(xv[j].y), h2 = f2bf(xv[j].z), h3 = f2bf(xv[j].w);
    unsigned short m0 = f2bf(xv[j].x - bf2f(h0)), m1 = f2bf(xv[j].y - bf2f(h1));
    unsigned short m2 = f2bf(xv[j].z - bf2f(h2)), m3 = f2bf(xv[j].w - bf2f(h3));
    uint2 ph, pl;
    ph.x = (uint32_t)h0 | ((uint32_t)h1 << 16); ph.y = (uint32_t)h2 | ((uint32_t)h3 << 16);
    pl.x = (uint32_t)m0 | ((uint32_t)m1 << 16); pl.y = (uint32_t)m2 | ((uint32_t)m3 << 16);
    int byteoff = (row * 128 + d0 * 2) ^ ((row & 7) << 4);
    *(uint2*)(smem + XH + byteoff) = ph;
    *(uint2*)(smem + XL + byteoff) = pl;
  }
  __syncthreads();

  bf16x8 xh[2], xl[2];
  {
    int row = w * 16 + lr;
#pragma unroll
    for (int dc = 0; dc < 2; ++dc) {
      int byteoff = (row * 128 + (dc * 32 + lg * 8) * 2) ^ ((row & 7) << 4);
      xh[dc] = *(const bf16x8*)(smem + XH + byteoff);
      xl[dc] = *(const bf16x8*)(smem + XL + byteoff);
    }
  }
  f32x4 acc[12];
#pragma unroll
  for (int nb = 0; nb < 12; ++nb) {
    f32x4 a = {0.f, 0.f, 0.f, 0.f};
    int og = nb * 16 + lr;
#pragma unroll
    for (int dc = 0; dc < 2; ++dc) {
      int byteoff = (og * 128 + (dc * 32 + lg * 8) * 2) ^ ((og & 7) << 4);
      bf16x8 bh = *(const bf16x8*)(smem + WTH + byteoff);
      bf16x8 bl = *(const bf16x8*)(smem + WTL + byteoff);
      a = __builtin_amdgcn_mfma_f32_16x16x32_bf16(bh, xh[dc], a, 0, 0, 0);
      a = __builtin_amdgcn_mfma_f32_16x16x32_bf16(bl, xh[dc], a, 0, 0, 0);
      a = __builtin_amdgcn_mfma_f32_16x16x32_bf16(bh, xl[dc], a, 0, 0, 0);
    }
    acc[nb] = a;
  }
  __syncthreads();  // done reading XH/XL; VTB may now alias

  const int tloc = w * 16 + lr;
  const size_t gt = (size_t)(rowbase + tloc);
#pragma unroll
  for (int nb = 0; nb < 12; ++nb) {
    int ogb = (nb & 3) * 16 + lg * 4;
    const float* bp = (nb < 4) ? bk : (nb < 8 ? bq : bv);
    float4 bias = *(const float4*)(bp + ogb);
    float v0 = acc[nb][0] + bias.x, v1 = acc[nb][1] + bias.y,
          v2 = acc[nb][2] + bias.z, v3 = acc[nb][3] + bias.w;
    if (nb < 4) {
      ushort4 hv;
      hv.x = f2h(v0); hv.y = f2h(v1); hv.z = f2h(v2); hv.w = f2h(v3);
      *(ushort4*)(kf + gt * 64 + ogb) = hv;
    } else if (nb < 8) {
      v0 *= SC_LOG2E; v1 *= SC_LOG2E; v2 *= SC_LOG2E; v3 *= SC_LOG2E;
      ushort4 hv, lv;
      hv.x = f2h(v0); lv.x = f2h(v0 - h2f(hv.x));
      hv.y = f2h(v1); lv.y = f2h(v1 - h2f(hv.y));
      hv.z = f2h(v2); lv.z = f2h(v2 - h2f(hv.z));
      hv.w = f2h(v3); lv.w = f2h(v3 - h2f(hv.w));
      *(ushort4*)(qfh + gt * 64 + ogb) = hv;
      *(ushort4*)(qfl + gt * 64 + ogb) = lv;
    } else {
      float vs[4] = {v0, v1, v2, v3};
#pragma unroll
      for (int r = 0; r < 4; ++r) {
        int o = ogb + r;
        int byteoff = (o * 128 + tloc * 2) ^ ((o & 7) << 4);
        *(unsigned short*)(smem + VTB + byteoff) = f2h(vs[r]);
      }
    }
  }
  __syncthreads();
  for (int cc = tid; cc < 512; cc += 256) {
    int o = cc >> 3, t0 = (cc & 7) * 8;
    int byteoff = (o * 128 + t0 * 2) ^ ((o & 7) << 4);
    uint4 v = *(const uint4*)(smem + VTB + byteoff);
    *(uint4*)(vt + ((size_t)bb * 64 + o) * NT + (size_t)(blk & 31) * 64 + t0) = v;
  }
}

// ---------------------------------------------------------------------------
// Kernel 2: flash attention — r20 f16 2-term kernel + r17 deferred-softmax
// pipeline. Body(i): STAGE(i+1) || QK(i)->S_cur (unread) || softmax(S_prev)
// + PV(i-1). K dbuf (2x16K), V tri-buf (3x16K) = 80KB -> 2 blocks/CU at
// (512,4). 8 waves = 2 q-groups x 4 key-quarters, QT=64 -> grid 512.
// ---------------------------------------------------------------------------
__global__ __launch_bounds__(512, 4) void attn_kernel(
    const unsigned short* __restrict__ kf, const unsigned short* __restrict__ qfh,
    const unsigned short* __restrict__ qfl, const unsigned short* __restrict__ vt,
    float* __restrict__ out)
{
  __shared__ __align__(16) char smem[81920];
  const int KB_A = 0, KB_B = 16384;
  const int VB_0 = 32768, VB_1 = 49152, VB_2 = 65536;
  const int MLB = 49152;   // epilogue m/l in VB_1 (dead after loop; final SMPV reads VB_0)
  const int tid = (int)threadIdx.x;
  const int l = tid & 63, w = tid >> 6;          // w in 0..7
  const int lq = l & 31;
  const bool hi = (l >= 32);
  const int hioff = hi ? 16 : 0;
  const int r = w & 1;                           // q-group: rows 32r..32r+31
  const int cc = w >> 1;                         // key quarter: keys 32cc..32cc+31
  const int lb = ((int)(blockIdx.x & 7) << 6) | ((int)blockIdx.x >> 3);
  const int bb = lb >> 5;
  const int qt = lb & 31;

  const char* k_base = (const char*)(kf + (size_t)bb * NT * 64);
  const char* v_base = (const char*)(vt + (size_t)bb * 64 * NT);

  // per tile: K 16KB [128 rows][128B], V^T 16KB [64 o][256B]; 16 chunks each
#define STAGE_TILE(kb_, vb_, it_)                                              \
  do {                                                                         \
    const char* k_t = k_base + (size_t)(it_) * 16384;                          \
    const char* v_tb = v_base + (size_t)(it_) * 256;                           \
    _Pragma("unroll")                                                          \
    for (int j = 0; j < 2; ++j) {                                              \
      int ch = 2 * w + j;                                                      \
      int d = ch * 1024 + l * 16;                                              \
      int swk = d ^ (((d >> 7) & 7) << 4);                                     \
      GLD_LDS16(k_t + swk, smem + (kb_) + ch * 1024);                          \
      int o = d >> 8;                                                          \
      int swv = (d & 255) ^ ((o & 7) << 4);                                    \
      GLD_LDS16(v_tb + (size_t)o * 4096 + swv, smem + (vb_) + ch * 1024);      \
    }                                                                          \
  } while (0)

  // prologue: stage tiles 0,1; Q hi/lo fragments to regs
  STAGE_TILE(KB_A, VB_0, 0);
  STAGE_TILE(KB_B, VB_1, 1);
  f16x8 Qh[4], Ql[4];
  {
    const char* qh_t = (const char*)qfh + ((size_t)bb * NT + (size_t)qt * QT) * 128;
    const char* ql_t = (const char*)qfl + ((size_t)bb * NT + (size_t)qt * QT) * 128;
    int qrow = r * 32 + lq;
#pragma unroll
    for (int dc = 0; dc < 4; ++dc) {
      Qh[dc] = *(const f16x8*)(qh_t + qrow * 128 + dc * 32 + hioff);
      Ql[dc] = *(const f16x8*)(ql_t + qrow * 128 + dc * 32 + hioff);
    }
  }
  asm volatile("s_waitcnt vmcnt(0)" ::: "memory");
  __builtin_amdgcn_s_barrier();
  asm volatile("" ::: "memory");

  f32x16 O0 = Z16, O1 = Z16;
  float mrun = -1e30f, lrun = 0.f;
  const int swr = (lq & 7) << 4;

  // QK^T of one tile from K buffer kb_: 2-term f16 (8 MFMAs)
#define QK_TILE(kb_, SC_)                                                      \
  {                                                                            \
    int krow_ = cc * 32 + lq;                                                  \
    __builtin_amdgcn_s_setprio(1);                                             \
    _Pragma("unroll")                                                          \
    for (int dc = 0; dc < 4; ++dc) {                                           \
      int cchunk_ = (dc * 32 + hioff) ^ swr;                                   \
      f16x8 Kf_ = *(const f16x8*)(smem + (kb_) + krow_ * 128 + cchunk_);       \
      SC_ = __builtin_amdgcn_mfma_f32_32x32x16_f16(Kf_, Qh[dc], SC_, 0, 0, 0); \
      SC_ = __builtin_amdgcn_mfma_f32_32x32x16_f16(Kf_, Ql[dc], SC_, 0, 0, 0); \
    }                                                                          \
    __builtin_amdgcn_s_setprio(0);                                             \
  }

  // softmax of a COMPLETED S tile + PV from V buffer vb_
#define SMPV(SP_, vb_)                                                         \
  {                                                                            \
    float a01 = fmaxf(SP_[0], SP_[1]),   a23 = fmaxf(SP_[2], SP_[3]);          \
    float a45 = fmaxf(SP_[4], SP_[5]),   a67 = fmaxf(SP_[6], SP_[7]);          \
    float a89 = fmaxf(SP_[8], SP_[9]),   aab = fmaxf(SP_[10], SP_[11]);        \
    float acd = fmaxf(SP_[12], SP_[13]), aef = fmaxf(SP_[14], SP_[15]);        \
    float pmax = fmaxf(fmaxf(fmaxf(a01, a23), fmaxf(a45, a67)),                \
                       fmaxf(fmaxf(a89, aab), fmaxf(acd, aef)));               \
    {                                                                          \
      auto sw_ = __builtin_amdgcn_permlane32_swap(uasf(pmax), uasf(pmax), false, false); \
      pmax = fmaxf(fasu(sw_[0]), fasu(sw_[1]));                                \
    }                                                                          \
    if (__any(pmax > mrun + 11.55f)) {                                         \
      float mnew = fmaxf(mrun, pmax);                                          \
      float alpha = EXP2F(mrun - mnew);                                        \
      O0 *= alpha; O1 *= alpha; lrun *= alpha; mrun = mnew;                    \
    }                                                                          \
    float p[16];                                                               \
    float ts = 0.f;                                                            \
    _Pragma("unroll")                                                          \
    for (int i = 0; i < 16; ++i) { p[i] = EXP2F(SP_[i] - mrun); ts += p[i]; }  \
    {                                                                          \
      auto sw_ = __builtin_amdgcn_permlane32_swap(uasf(ts), uasf(ts), false, false); \
      ts = fasu(sw_[0]) + fasu(sw_[1]);                                        \
    }                                                                          \
    lrun += ts;                                                                \
    __builtin_amdgcn_s_setprio(1);                                             \
    _Pragma("unroll")                                                          \
    for (int kc = 0; kc < 2; ++kc) {                                           \
      const int b_ = 8 * kc;                                                   \
      uint32_t X0 = pkh(p[b_+0], p[b_+1]);                                     \
      uint32_t X1 = pkh(p[b_+2], p[b_+3]);                                     \
      uint32_t Y0 = pkh(p[b_+4], p[b_+5]);                                     \
      uint32_t Y1 = pkh(p[b_+6], p[b_+7]);                                     \
      auto sw0_ = __builtin_amdgcn_permlane32_swap(X0, Y0, false, false);      \
      auto sw1_ = __builtin_amdgcn_permlane32_swap(X1, Y1, false, false);      \
      union { uint32_t u[4]; f16x8 v; } cvb_;                                  \
      cvb_.u[0] = sw0_[0]; cvb_.u[1] = sw1_[0];                                \
      cvb_.u[2] = sw0_[1]; cvb_.u[3] = sw1_[1];                                \
      int vcol_ = 64 * cc + 32 * kc + hioff;                                   \
      f16x8 Av0_ = *(const f16x8*)(smem + (vb_) + lq * 256 + (vcol_ ^ swr));   \
      f16x8 Av1_ = *(const f16x8*)(smem + (vb_) + (32 + lq) * 256 + (vcol_ ^ swr)); \
      O0 = __builtin_amdgcn_mfma_f32_32x32x16_f16(Av0_, cvb_.v, O0, 0, 0, 0);  \
      O1 = __builtin_amdgcn_mfma_f32_32x32x16_f16(Av1_, cvb_.v, O1, 0, 0, 0);  \
    }                                                                          \
    __builtin_amdgcn_s_setprio(0);                                             \
  }

  // QK(0) -> SA; barrier so body(1)'s stage of tile 2 can reuse KB_A safely
  f32x16 SA = Z16, SB = Z16;
  QK_TILE(KB_A, SA);
  asm volatile("s_waitcnt lgkmcnt(0)" ::: "memory");
  __builtin_amdgcn_s_barrier();
  asm volatile("" ::: "memory");

  int kbC = KB_B, kbN = KB_A;
  int vbP = VB_0, vbC = VB_1, vbN = VB_2;

#define BODY(i_, SP_, SC_, STG_)                                               \
  {                                                                            \
    if (STG_) STAGE_TILE(kbN, vbN, (i_) + 1);                                  \
    SC_ = Z16;                                                                 \
    QK_TILE(kbC, SC_);                                                         \
    SMPV(SP_, vbP);                                                            \
    asm volatile("s_waitcnt vmcnt(0)" ::: "memory");                           \
    __builtin_amdgcn_s_barrier();                                              \
    asm volatile("" ::: "memory");                                             \
    __builtin_amdgcn_sched_barrier(0);                                         \
  }
#define ROT()                                                                  \
  { int t_ = vbP; vbP = vbC; vbC = vbN; vbN = t_;                              \
    t_ = kbC; kbC = kbN; kbN = t_; }

#pragma unroll 1
  for (int ib = 0; ib < 7; ++ib) {
    BODY(2 * ib + 1, SA, SB, 1)
    ROT()
    BODY(2 * ib + 2, SB, SA, 1)
    ROT()
  }
  BODY(15, SA, SB, 0)
  // tail: softmax + PV for tile 15 (V(15) lives in vbC = VB_0 after 14 ROTs)
  SMPV(SB, vbC);

  // --- epilogue: 2-stage 4-way split-K merge, direct f32x4 stores
  const int lsw = (l & 7) << 4;
#define DUMP(idx_)                                                             \
  {                                                                            \
    char* dd = smem + (idx_) * 8192 + l * 128;                                 \
    _Pragma("unroll")                                                          \
    for (int g = 0; g < 4; ++g) {                                              \
      f32x4 t0, t1;                                                            \
      _Pragma("unroll")                                                        \
      for (int j = 0; j < 4; ++j) { t0[j] = O0[4*g+j]; t1[j] = O1[4*g+j]; }    \
      *(f32x4*)(dd + ((g * 16) ^ lsw)) = t0;                                   \
      *(f32x4*)(dd + ((64 + g * 16) ^ lsw)) = t1;                              \
    }                                                                          \
    *(float*)(smem + MLB + (idx_) * 256 + lq * 8) = mrun;                      \
    *(float*)(smem + MLB + (idx_) * 256 + lq * 8 + 4) = lrun;                  \
  }
#define MERGE(idx_)                                                            \
  {                                                                            \
    const char* ds = smem + (idx_) * 8192 + l * 128;                           \
    float m1 = *(const float*)(smem + MLB + (idx_) * 256 + lq * 8);            \
    float l1 = *(const float*)(smem + MLB + (idx_) * 256 + lq * 8 + 4);        \
    float M = fmaxf(mrun, m1);                                                 \
    float a0 = EXP2F(mrun - M);                                                \
    float a1 = EXP2F(m1 - M);                                                  \
    lrun = lrun * a0 + l1 * a1;                                                \
    mrun = M;                                                                  \
    _Pragma("unroll")                                                          \
    for (int g = 0; g < 4; ++g) {                                              \
      f32x4 o1a = *(const f32x4*)(ds + ((g * 16) ^ lsw));                      \
      f32x4 o1b = *(const f32x4*)(ds + ((64 + g * 16) ^ lsw));                 \
      _Pragma("unroll")                                                        \
      for (int j = 0; j < 4; ++j) {                                            \
        O0[4*g+j] = O0[4*g+j] * a0 + o1a[j] * a1;                              \
        O1[4*g+j] = O1[4*g+j] * a0 + o1b[j] * a1;                              \
      }                                                                        \
    }                                                                          \
  }
  __syncthreads();   // final SMPV reads drained before DUMP aliases K bufs
  if (cc & 1) DUMP(r * 2 + (cc >> 1));      // cc=1 -> idx 2r, cc=3 -> idx 2r+1
  __syncthreads();
  if (!(cc & 1)) MERGE(r * 2 + (cc >> 1));  // cc=0 takes cc=1, cc=2 takes cc=3
  __syncthreads();
  if (cc == 2) DUMP(r * 2 + 1);
  __syncthreads();
  if (cc == 0) {
    MERGE(r * 2 + 1);
    float inv = 1.0f / lrun;
    float* orow = out + ((size_t)bb * NT + (size_t)qt * QT + r * 32 + lq) * 64;
#pragma unroll
    for (int g = 0; g < 4; ++g) {
      int d0 = 8 * g + (hi ? 4 : 0);
      f32x4 s0, s1;
#pragma unroll
      for (int j = 0; j < 4; ++j) { s0[j] = O0[4*g+j] * inv; s1[j] = O1[4*g+j] * inv; }
      *(f32x4*)(orow + d0) = s0;
      *(f32x4*)(orow + d0 + 32) = s1;
    }
  }
#undef DUMP
#undef MERGE
#undef BODY
#undef ROT
#undef SMPV
#undef QK_TILE
#undef STAGE_TILE
}

extern "C" void kernel_launch(void* const* d_in, const int* in_sizes, int n_in,
                              void* d_out, int out_size, void* d_ws, size_t ws_size,
                              hipStream_t stream) {
  const float* x  = (const float*)d_in[0];
  const float* Wk = (const float*)d_in[1];
  const float* bk = (const float*)d_in[2];
  const float* Wq = (const float*)d_in[3];
  const float* bq = (const float*)d_in[4];
  const float* Wv = (const float*)d_in[5];
  const float* bv = (const float*)d_in[6];
  float* out = (float*)d_out;

  const size_t NE = (size_t)NBATCH * NT * 64;
  unsigned short* ws = (unsigned short*)d_ws;
  unsigned short* kf  = ws;
  unsigned short* qfh = ws + NE;
  unsigned short* qfl = ws + 2 * NE;
  unsigned short* vt  = ws + 3 * NE;
  unsigned short* wt_hi = ws + 4 * NE;
  unsigned short* wt_lo = wt_hi + 192 * 64;

  prep_w<<<dim3(3), dim3(256), 0, stream>>>(Wk, Wq, Wv, wt_hi, wt_lo);
  proj_kernel<<<dim3((NBATCH * NT) / 64), dim3(256), 0, stream>>>(
      x, wt_hi, wt_lo, bk, bq, bv, kf, qfh, qfl, vt);
  attn_kernel<<<dim3(NBATCH * (NT / QT)), dim3(512), 0, stream>>>(
      kf, qfh, qfl, vt, out);
}

// Round 22
// 61.031 us; speedup vs baseline: 1.0562x; 1.0562x over previous
//
#include <hip/hip_runtime.h>
#include <hip/hip_bf16.h>
#include <stdint.h>

#define NBATCH 16
#define NT 2048
#define NC 64
#define QT 64
#define KT 128
#define SC_LOG2E 11.5415603f  // 8 * log2(e)

typedef __bf16 bf16x8 __attribute__((ext_vector_type(8)));
typedef _Float16 f16x8 __attribute__((ext_vector_type(8)));
typedef float f32x4 __attribute__((ext_vector_type(4)));
typedef float f32x16 __attribute__((ext_vector_type(16)));

#define Z16 {0.f,0.f,0.f,0.f,0.f,0.f,0.f,0.f,0.f,0.f,0.f,0.f,0.f,0.f,0.f,0.f}

extern "C" __device__ float __ocml_native_exp2_f32(float);
#define EXP2F(x) __ocml_native_exp2_f32(x)

static __device__ __forceinline__ unsigned short f2bf(float f) {
  __bf16 h = (__bf16)f;
  union { __bf16 h; unsigned short u; } a; a.h = h; return a.u;
}
static __device__ __forceinline__ float bf2f(unsigned short h) {
  union { uint32_t u; float f; } a; a.u = ((uint32_t)h) << 16;
  return a.f;
}
static __device__ __forceinline__ unsigned short f2h(float f) {
  _Float16 h = (_Float16)f;  // v_cvt_f16_f32, RTNE
  union { _Float16 h; unsigned short u; } a; a.h = h; return a.u;
}
static __device__ __forceinline__ float h2f(unsigned short u) {
  union { unsigned short u; _Float16 h; } a; a.u = u; return (float)a.h;
}
static __device__ __forceinline__ float fasu(uint32_t u) {
  union { uint32_t u; float f; } a; a.u = u; return a.f;
}
static __device__ __forceinline__ uint32_t uasf(float f) {
  union { float f; uint32_t u; } a; a.f = f; return a.u;
}
static __device__ __forceinline__ uint32_t pkh(float a, float b) {
  auto h = __builtin_amdgcn_cvt_pkrtz(a, b);   // packed 2 x f16
  union { decltype(h) v; uint32_t u; } c; c.v = h; return c.u;
}

#define GLD_LDS16(gsrc, ldst)                                                  \
  __builtin_amdgcn_global_load_lds(                                            \
      (const __attribute__((address_space(1))) void*)(gsrc),                   \
      (__attribute__((address_space(3))) void*)(ldst), 16, 0, 0)

// ---------------------------------------------------------------------------
// Kernel 0: one-time W transpose + hi/lo bf16 split. 3 blocks (k,q,v).
// ---------------------------------------------------------------------------
__global__ __launch_bounds__(256, 2) void prep_w(
    const float* __restrict__ Wk, const float* __restrict__ Wq,
    const float* __restrict__ Wv,
    unsigned short* __restrict__ wt_hi, unsigned short* __restrict__ wt_lo)
{
  __shared__ unsigned short hbuf[64][66];
  __shared__ unsigned short lbuf[64][66];
  const int m = (int)blockIdx.x;
  const float* Wm = (m == 0) ? Wk : (m == 1 ? Wq : Wv);
  const int tid = (int)threadIdx.x;
  for (int idx = tid; idx < 1024; idx += 256) {
    int c = idx >> 4, o4 = (idx & 15) * 4;
    float4 v = *(const float4*)(Wm + c * 64 + o4);
    float vals[4] = {v.x, v.y, v.z, v.w};
#pragma unroll
    for (int j = 0; j < 4; ++j) {
      unsigned short h = f2bf(vals[j]);
      hbuf[o4 + j][c] = h;
      lbuf[o4 + j][c] = f2bf(vals[j] - bf2f(h));
    }
  }
  __syncthreads();
  for (int idx = tid; idx < 1024; idx += 256) {
    int o = idx >> 4, c0 = (idx & 15) * 4;
    ushort4 hv, lv;
    hv.x = hbuf[o][c0]; hv.y = hbuf[o][c0 + 1];
    hv.z = hbuf[o][c0 + 2]; hv.w = hbuf[o][c0 + 3];
    lv.x = lbuf[o][c0]; lv.y = lbuf[o][c0 + 1];
    lv.z = lbuf[o][c0 + 2]; lv.w = lbuf[o][c0 + 3];
    *(ushort4*)(wt_hi + (size_t)(m * 64 + o) * 64 + c0) = hv;
    *(ushort4*)(wt_lo + (size_t)(m * 64 + o) * 64 + c0) = lv;
  }
}

// ---------------------------------------------------------------------------
// Kernel 1: q,k,v projections. Internal math bf16 hi/lo MFMA (validated);
// outputs: kf (f16), qfh/qfl (f16 hi/lo of pre-scaled q), vt (f16, [B][64][T]).
// ---------------------------------------------------------------------------
__global__ __launch_bounds__(256, 2) void proj_kernel(
    const float* __restrict__ x,
    const unsigned short* __restrict__ wt_hi, const unsigned short* __restrict__ wt_lo,
    const float* __restrict__ bk, const float* __restrict__ bq, const float* __restrict__ bv,
    unsigned short* __restrict__ kf, unsigned short* __restrict__ qfh,
    unsigned short* __restrict__ qfl, unsigned short* __restrict__ vt)
{
  __shared__ __align__(16) char smem[65536];
  const int XH = 0, XL = 8192, WTH = 16384, WTL = 40960, VTB = 0; // VTB aliases XH
  const int tid = (int)threadIdx.x;
  const int l = tid & 63, w = tid >> 6;
  const int lr = l & 15, lg = l >> 4;
  const int blk = (int)blockIdx.x;
  const int rowbase = blk * 64;
  const int bb = blk >> 5;          // 32 blocks per batch

  float4 xv[4];
#pragma unroll
  for (int j = 0; j < 4; ++j) {
    int c = tid + j * 256;
    int row = c >> 4, d0 = (c & 15) * 4;
    xv[j] = *(const float4*)(x + (size_t)(rowbase + row) * NC + d0);
  }
#pragma unroll
  for (int ch4 = 0; ch4 < 6; ++ch4) {
    int ch = ch4 * 4 + w;
    int d = ch * 1024 + l * 16;
    int swk = d ^ (((d >> 7) & 7) << 4);
    GLD_LDS16((const char*)wt_hi + swk, smem + WTH + ch * 1024);
    GLD_LDS16((const char*)wt_lo + swk, smem + WTL + ch * 1024);
  }
#pragma unroll
  for (int j = 0; j < 4; ++j) {
    int c = tid + j * 256;
    int row = c >> 4, d0 = (c & 15) * 4;
    unsigned short h0 = f2bf(xv[j].x), h1 = f2bf(xv[j].y), h2 = f2bf(xv[j].z), h3 = f2bf(xv[j].w);
    unsigned short m0 = f2bf(xv[j].x - bf2f(h0)), m1 = f2bf(xv[j].y - bf2f(h1));
    unsigned short m2 = f2bf(xv[j].z - bf2f(h2)), m3 = f2bf(xv[j].w - bf2f(h3));
    uint2 ph, pl;
    ph.x = (uint32_t)h0 | ((uint32_t)h1 << 16); ph.y = (uint32_t)h2 | ((uint32_t)h3 << 16);
    pl.x = (uint32_t)m0 | ((uint32_t)m1 << 16); pl.y = (uint32_t)m2 | ((uint32_t)m3 << 16);
    int byteoff = (row * 128 + d0 * 2) ^ ((row & 7) << 4);
    *(uint2*)(smem + XH + byteoff) = ph;
    *(uint2*)(smem + XL + byteoff) = pl;
  }
  __syncthreads();

  bf16x8 xh[2], xl[2];
  {
    int row = w * 16 + lr;
#pragma unroll
    for (int dc = 0; dc < 2; ++dc) {
      int byteoff = (row * 128 + (dc * 32 + lg * 8) * 2) ^ ((row & 7) << 4);
      xh[dc] = *(const bf16x8*)(smem + XH + byteoff);
      xl[dc] = *(const bf16x8*)(smem + XL + byteoff);
    }
  }
  f32x4 acc[12];
#pragma unroll
  for (int nb = 0; nb < 12; ++nb) {
    f32x4 a = {0.f, 0.f, 0.f, 0.f};
    int og = nb * 16 + lr;
#pragma unroll
    for (int dc = 0; dc < 2; ++dc) {
      int byteoff = (og * 128 + (dc * 32 + lg * 8) * 2) ^ ((og & 7) << 4);
      bf16x8 bh = *(const bf16x8*)(smem + WTH + byteoff);
      bf16x8 bl = *(const bf16x8*)(smem + WTL + byteoff);
      a = __builtin_amdgcn_mfma_f32_16x16x32_bf16(bh, xh[dc], a, 0, 0, 0);
      a = __builtin_amdgcn_mfma_f32_16x16x32_bf16(bl, xh[dc], a, 0, 0, 0);
      a = __builtin_amdgcn_mfma_f32_16x16x32_bf16(bh, xl[dc], a, 0, 0, 0);
    }
    acc[nb] = a;
  }
  __syncthreads();  // done reading XH/XL; VTB may now alias

  const int tloc = w * 16 + lr;
  const size_t gt = (size_t)(rowbase + tloc);
#pragma unroll
  for (int nb = 0; nb < 12; ++nb) {
    int ogb = (nb & 3) * 16 + lg * 4;
    const float* bp = (nb < 4) ? bk : (nb < 8 ? bq : bv);
    float4 bias = *(const float4*)(bp + ogb);
    float v0 = acc[nb][0] + bias.x, v1 = acc[nb][1] + bias.y,
          v2 = acc[nb][2] + bias.z, v3 = acc[nb][3] + bias.w;
    if (nb < 4) {
      ushort4 hv;
      hv.x = f2h(v0); hv.y = f2h(v1); hv.z = f2h(v2); hv.w = f2h(v3);
      *(ushort4*)(kf + gt * 64 + ogb) = hv;
    } else if (nb < 8) {
      v0 *= SC_LOG2E; v1 *= SC_LOG2E; v2 *= SC_LOG2E; v3 *= SC_LOG2E;
      ushort4 hv, lv;
      hv.x = f2h(v0); lv.x = f2h(v0 - h2f(hv.x));
      hv.y = f2h(v1); lv.y = f2h(v1 - h2f(hv.y));
      hv.z = f2h(v2); lv.z = f2h(v2 - h2f(hv.z));
      hv.w = f2h(v3); lv.w = f2h(v3 - h2f(hv.w));
      *(ushort4*)(qfh + gt * 64 + ogb) = hv;
      *(ushort4*)(qfl + gt * 64 + ogb) = lv;
    } else {
      float vs[4] = {v0, v1, v2, v3};
#pragma unroll
      for (int r = 0; r < 4; ++r) {
        int o = ogb + r;
        int byteoff = (o * 128 + tloc * 2) ^ ((o & 7) << 4);
        *(unsigned short*)(smem + VTB + byteoff) = f2h(vs[r]);
      }
    }
  }
  __syncthreads();
  for (int cc = tid; cc < 512; cc += 256) {
    int o = cc >> 3, t0 = (cc & 7) * 8;
    int byteoff = (o * 128 + t0 * 2) ^ ((o & 7) << 4);
    uint4 v = *(const uint4*)(smem + VTB + byteoff);
    *(uint4*)(vt + ((size_t)bb * 64 + o) * NT + (size_t)(blk & 31) * 64 + t0) = v;
  }
}

// ---------------------------------------------------------------------------
// Kernel 2: flash attention — r20 f16 2-term kernel (validated 41.6 us) with
// two VALU cuts: defer-max window 11.55 -> 15.5 (P <= 2^15.5 < f16 max;
// fewer O-rescale passes) and max3-shaped reduction tree.
// 512 thr = 8 waves = 2 q-groups x 4 key-quarters; QT=64 -> grid 512.
// LDS 64KB (K dbuf 2x16K + V dbuf 2x16K) -> 2 blocks/CU at (512,4).
// ---------------------------------------------------------------------------
__global__ __launch_bounds__(512, 4) void attn_kernel(
    const unsigned short* __restrict__ kf, const unsigned short* __restrict__ qfh,
    const unsigned short* __restrict__ qfl, const unsigned short* __restrict__ vt,
    float* __restrict__ out)
{
  __shared__ __align__(16) char smem[65536];
  const int KB_A = 0, KB_B = 16384;
  const int VB_0 = 32768, VB_1 = 49152;
  const int MLB = 49152;   // epilogue m/l (post-loop; DUMP slots use 0..32K)
  const int tid = (int)threadIdx.x;
  const int l = tid & 63, w = tid >> 6;          // w in 0..7
  const int lq = l & 31;
  const bool hi = (l >= 32);
  const int hioff = hi ? 16 : 0;
  const int r = w & 1;                           // q-group: rows 32r..32r+31
  const int cc = w >> 1;                         // key quarter: keys 32cc..32cc+31
  const int lb = ((int)(blockIdx.x & 7) << 6) | ((int)blockIdx.x >> 3);
  const int bb = lb >> 5;
  const int qt = lb & 31;

  const char* k_base = (const char*)(kf + (size_t)bb * NT * 64);
  const char* v_base = (const char*)(vt + (size_t)bb * 64 * NT);

  // per tile: K 16KB [128 rows][128B], V^T 16KB [64 o][256B]; 16 chunks each
#define STAGE_TILE(kb_, vb_, it_)                                              \
  do {                                                                         \
    const char* k_t = k_base + (size_t)(it_) * 16384;                          \
    const char* v_tb = v_base + (size_t)(it_) * 256;                           \
    _Pragma("unroll")                                                          \
    for (int j = 0; j < 2; ++j) {                                              \
      int ch = 2 * w + j;                                                      \
      int d = ch * 1024 + l * 16;                                              \
      int swk = d ^ (((d >> 7) & 7) << 4);                                     \
      GLD_LDS16(k_t + swk, smem + (kb_) + ch * 1024);                          \
      int o = d >> 8;                                                          \
      int swv = (d & 255) ^ ((o & 7) << 4);                                    \
      GLD_LDS16(v_tb + (size_t)o * 4096 + swv, smem + (vb_) + ch * 1024);      \
    }                                                                          \
  } while (0)

  // prologue: stage tile 0; Q hi/lo fragments to regs
  STAGE_TILE(KB_A, VB_0, 0);
  f16x8 Qh[4], Ql[4];
  {
    const char* qh_t = (const char*)qfh + ((size_t)bb * NT + (size_t)qt * QT) * 128;
    const char* ql_t = (const char*)qfl + ((size_t)bb * NT + (size_t)qt * QT) * 128;
    int qrow = r * 32 + lq;
#pragma unroll
    for (int dc = 0; dc < 4; ++dc) {
      Qh[dc] = *(const f16x8*)(qh_t + qrow * 128 + dc * 32 + hioff);
      Ql[dc] = *(const f16x8*)(ql_t + qrow * 128 + dc * 32 + hioff);
    }
  }
  asm volatile("s_waitcnt vmcnt(0)" ::: "memory");
  __builtin_amdgcn_s_barrier();
  asm volatile("" ::: "memory");

  f32x16 O0 = Z16, O1 = Z16;
  float mrun = -1e30f, lrun = 0.f;
  const int swr = (lq & 7) << 4;

  for (int it = 0; it < NT / KT; ++it) {
    const int cbk = (it & 1) ? KB_B : KB_A;
    const int cbv = (it & 1) ? VB_1 : VB_0;
    if (it + 1 < NT / KT)
      STAGE_TILE((it & 1) ? KB_A : KB_B, (it & 1) ? VB_0 : VB_1, it + 1);

    // --- S^T[key][q] = K · (Q_h + Q_l), 2-term f16 (8 MFMAs)
    f32x16 S = Z16;
    __builtin_amdgcn_s_setprio(1);
#pragma unroll
    for (int dc = 0; dc < 4; ++dc) {
      int krow = cc * 32 + lq;
      int cchunk = (dc * 32 + hioff) ^ swr;
      f16x8 Kf = *(const f16x8*)(smem + cbk + krow * 128 + cchunk);
      S = __builtin_amdgcn_mfma_f32_32x32x16_f16(Kf, Qh[dc], S, 0, 0, 0);
      S = __builtin_amdgcn_mfma_f32_32x32x16_f16(Kf, Ql[dc], S, 0, 0, 0);
    }
    __builtin_amdgcn_s_setprio(0);

    // --- online softmax; max3-shaped tree + permlane cross-half reduce
    float t0 = fmaxf(fmaxf(S[0], S[1]), S[2]);
    float t1 = fmaxf(fmaxf(S[3], S[4]), S[5]);
    float t2 = fmaxf(fmaxf(S[6], S[7]), S[8]);
    float t3 = fmaxf(fmaxf(S[9], S[10]), S[11]);
    float t4 = fmaxf(fmaxf(S[12], S[13]), S[14]);
    float pmax = fmaxf(fmaxf(fmaxf(t0, t1), t2), fmaxf(fmaxf(t3, t4), S[15]));
    {
      auto sw = __builtin_amdgcn_permlane32_swap(uasf(pmax), uasf(pmax), false, false);
      pmax = fmaxf(fasu(sw[0]), fasu(sw[1]));
    }
    if (__any(pmax > mrun + 15.5f)) {       // wide defer window (P <= 2^15.5)
      float mnew = fmaxf(mrun, pmax);
      float alpha = EXP2F(mrun - mnew);
      O0 *= alpha; O1 *= alpha; lrun *= alpha; mrun = mnew;
    }
    float p[16];
    float ts = 0.f;
#pragma unroll
    for (int i = 0; i < 16; ++i) { p[i] = EXP2F(S[i] - mrun); ts += p[i]; }
    {
      auto sw = __builtin_amdgcn_permlane32_swap(uasf(ts), uasf(ts), false, false);
      ts = fasu(sw[0]) + fasu(sw[1]);
    }
    lrun += ts;

    // --- O^T += V^T · P^T  (A = V^T frag from LDS, B = P^T in-register f16)
    __builtin_amdgcn_s_setprio(1);
#pragma unroll
    for (int kc = 0; kc < 2; ++kc) {
      const int b_ = 8 * kc;
      uint32_t X0 = pkh(p[b_+0], p[b_+1]);
      uint32_t X1 = pkh(p[b_+2], p[b_+3]);
      uint32_t Y0 = pkh(p[b_+4], p[b_+5]);
      uint32_t Y1 = pkh(p[b_+6], p[b_+7]);
      auto sw0 = __builtin_amdgcn_permlane32_swap(X0, Y0, false, false);
      auto sw1 = __builtin_amdgcn_permlane32_swap(X1, Y1, false, false);
      union { uint32_t u[4]; f16x8 v; } cvb;
      cvb.u[0] = sw0[0]; cvb.u[1] = sw1[0];
      cvb.u[2] = sw0[1]; cvb.u[3] = sw1[1];
      int vcol = 64 * cc + 32 * kc + hioff;
      f16x8 Av0 = *(const f16x8*)(smem + cbv + lq * 256 + (vcol ^ swr));
      f16x8 Av1 = *(const f16x8*)(smem + cbv + (32 + lq) * 256 + (vcol ^ swr));
      O0 = __builtin_amdgcn_mfma_f32_32x32x16_f16(Av0, cvb.v, O0, 0, 0, 0);
      O1 = __builtin_amdgcn_mfma_f32_32x32x16_f16(Av1, cvb.v, O1, 0, 0, 0);
    }
    __builtin_amdgcn_s_setprio(0);

    // tail: drain next tile's loads (flew during compute), then publish
    asm volatile("s_waitcnt vmcnt(0)" ::: "memory");
    __builtin_amdgcn_s_barrier();
    asm volatile("" ::: "memory");
    __builtin_amdgcn_sched_barrier(0);
  }

  // --- epilogue: 2-stage 4-way split-K merge, direct f32x4 stores
  const int lsw = (l & 7) << 4;
#define DUMP(idx_)                                                             \
  {                                                                            \
    char* dd = smem + (idx_) * 8192 + l * 128;                                 \
    _Pragma("unroll")                                                          \
    for (int g = 0; g < 4; ++g) {                                              \
      f32x4 t0, t1;                                                            \
      _Pragma("unroll")                                                        \
      for (int j = 0; j < 4; ++j) { t0[j] = O0[4*g+j]; t1[j] = O1[4*g+j]; }    \
      *(f32x4*)(dd + ((g * 16) ^ lsw)) = t0;                                   \
      *(f32x4*)(dd + ((64 + g * 16) ^ lsw)) = t1;                              \
    }                                                                          \
    *(float*)(smem + MLB + (idx_) * 256 + lq * 8) = mrun;                      \
    *(float*)(smem + MLB + (idx_) * 256 + lq * 8 + 4) = lrun;                  \
  }
#define MERGE(idx_)                                                            \
  {                                                                            \
    const char* ds = smem + (idx_) * 8192 + l * 128;                           \
    float m1 = *(const float*)(smem + MLB + (idx_) * 256 + lq * 8);            \
    float l1 = *(const float*)(smem + MLB + (idx_) * 256 + lq * 8 + 4);        \
    float M = fmaxf(mrun, m1);                                                 \
    float a0 = EXP2F(mrun - M);                                                \
    float a1 = EXP2F(m1 - M);                                                  \
    lrun = lrun * a0 + l1 * a1;                                                \
    mrun = M;                                                                  \
    _Pragma("unroll")                                                          \
    for (int g = 0; g < 4; ++g) {                                              \
      f32x4 o1a = *(const f32x4*)(ds + ((g * 16) ^ lsw));                      \
      f32x4 o1b = *(const f32x4*)(ds + ((64 + g * 16) ^ lsw));                 \
      _Pragma("unroll")                                                        \
      for (int j = 0; j < 4; ++j) {                                            \
        O0[4*g+j] = O0[4*g+j] * a0 + o1a[j] * a1;                              \
        O1[4*g+j] = O1[4*g+j] * a0 + o1b[j] * a1;                              \
      }                                                                        \
    }                                                                          \
  }
  if (cc & 1) DUMP(r * 2 + (cc >> 1));      // cc=1 -> idx 2r, cc=3 -> idx 2r+1
  __syncthreads();
  if (!(cc & 1)) MERGE(r * 2 + (cc >> 1));  // cc=0 takes cc=1, cc=2 takes cc=3
  __syncthreads();
  if (cc == 2) DUMP(r * 2 + 1);
  __syncthreads();
  if (cc == 0) {
    MERGE(r * 2 + 1);
    float inv = 1.0f / lrun;
    float* orow = out + ((size_t)bb * NT + (size_t)qt * QT + r * 32 + lq) * 64;
#pragma unroll
    for (int g = 0; g < 4; ++g) {
      int d0 = 8 * g + (hi ? 4 : 0);
      f32x4 s0, s1;
#pragma unroll
      for (int j = 0; j < 4; ++j) { s0[j] = O0[4*g+j] * inv; s1[j] = O1[4*g+j] * inv; }
      *(f32x4*)(orow + d0) = s0;
      *(f32x4*)(orow + d0 + 32) = s1;
    }
  }
#undef DUMP
#undef MERGE
#undef STAGE_TILE
}

extern "C" void kernel_launch(void* const* d_in, const int* in_sizes, int n_in,
                              void* d_out, int out_size, void* d_ws, size_t ws_size,
                              hipStream_t stream) {
  const float* x  = (const float*)d_in[0];
  const float* Wk = (const float*)d_in[1];
  const float* bk = (const float*)d_in[2];
  const float* Wq = (const float*)d_in[3];
  const float* bq = (const float*)d_in[4];
  const float* Wv = (const float*)d_in[5];
  const float* bv = (const float*)d_in[6];
  float* out = (float*)d_out;

  const size_t NE = (size_t)NBATCH * NT * 64;
  unsigned short* ws = (unsigned short*)d_ws;
  unsigned short* kf  = ws;
  unsigned short* qfh = ws + NE;
  unsigned short* qfl = ws + 2 * NE;
  unsigned short* vt  = ws + 3 * NE;
  unsigned short* wt_hi = ws + 4 * NE;
  unsigned short* wt_lo = wt_hi + 192 * 64;

  prep_w<<<dim3(3), dim3(256), 0, stream>>>(Wk, Wq, Wv, wt_hi, wt_lo);
  proj_kernel<<<dim3((NBATCH * NT) / 64), dim3(256), 0, stream>>>(
      x, wt_hi, wt_lo, bk, bq, bv, kf, qfh, qfl, vt);
  attn_kernel<<<dim3(NBATCH * (NT / QT)), dim3(512), 0, stream>>>(
      kf, qfh, qfl, vt, out);
}